// Round 3
// baseline (436.690 us; speedup 1.0000x reference)
//
#include <hip/hip_runtime.h>

// modConv: y = demod(b,fo) * conv3x3(x * s(b,fi), w * w_scale)
// bf16 MFMA implicit GEMM (M=fo, N=pixels, K=fi, 9 taps accumulated).
// R3: 2-wave blocks (128 thr, 128fo x 128px tile, 16KB/buffer dbuf) -> 4
//     independent barrier groups per CU so drains overlap across blocks.
//     Prep reductions spread wave-per-output (1024 blocks, was 16).

typedef __bf16 bf16_t;
typedef __bf16 bf16x8 __attribute__((ext_vector_type(8)));
typedef float floatx4 __attribute__((ext_vector_type(4)));
typedef float floatx4v __attribute__((ext_vector_type(4)));

#define HW_ 4096
#define FCSCALE 0.04419417382415922f   /* 512^-0.5 */
#define WSCALE  0.014731391274719742f  /* (512*9)^-0.5 */

__device__ __forceinline__ void gload_lds16(const bf16_t* g, bf16_t* l) {
  __builtin_amdgcn_global_load_lds(
      (const __attribute__((address_space(1))) void*)g,
      (__attribute__((address_space(3))) void*)l, 16, 0, 0);
}

// s[o] for o=b*512+fi: one wave per output, coalesced 2KB row read, shfl reduce
__global__ void k_style(const float* __restrict__ style, const float* __restrict__ fc_w,
                        const float* __restrict__ fc_b, float* __restrict__ s_out) {
  int o = blockIdx.x * 4 + (threadIdx.x >> 6);  // 0..4095
  int lane = threadIdx.x & 63;
  int b = o >> 9, fi = o & 511;
  const float4* st = (const float4*)(style + b * 512);
  const float4* fw = (const float4*)(fc_w + (size_t)fi * 512);
  float4 a0 = st[lane * 2],     w0 = fw[lane * 2];
  float4 a1 = st[lane * 2 + 1], w1 = fw[lane * 2 + 1];
  float acc = a0.x * w0.x + a0.y * w0.y + a0.z * w0.z + a0.w * w0.w
            + a1.x * w1.x + a1.y * w1.y + a1.z * w1.z + a1.w * w1.w;
#pragma unroll
  for (int d = 32; d >= 1; d >>= 1) acc += __shfl_xor(acc, d, 64);
  if (lane == 0) s_out[o] = acc * FCSCALE + fc_b[fi];
}

// wsq[fo][fi] = sum_tap (w*ws)^2 ; wt[tap][fo][fi] = bf16(w*ws)
__global__ void k_wsq_wt(const float* __restrict__ w, float* __restrict__ wsq,
                         bf16_t* __restrict__ wt) {
  int idx = blockIdx.x * 256 + threadIdx.x;     // fo*512+fi
  const float* wp = w + (size_t)idx * 9;
  float v[9], q = 0.f;
#pragma unroll
  for (int k = 0; k < 9; ++k) { v[k] = wp[k] * WSCALE; q += v[k] * v[k]; }
  wsq[idx] = q;
#pragma unroll
  for (int k = 0; k < 9; ++k) wt[(size_t)k * 262144 + idx] = (bf16_t)v[k];
}

// d[o] = rsqrt(sum_fi wsq[fo][fi]*s[b][fi]^2 + eps): wave per output
__global__ void k_demod(const float* __restrict__ wsq, const float* __restrict__ s,
                        float* __restrict__ dcoef) {
  int o = blockIdx.x * 4 + (threadIdx.x >> 6);  // 0..4095 = b*512+fo
  int lane = threadIdx.x & 63;
  int b = o >> 9, fo = o & 511;
  const float4* wq = (const float4*)(wsq + (size_t)fo * 512);
  const float4* sp = (const float4*)(s + b * 512);
  float acc = 0.f;
#pragma unroll
  for (int i = 0; i < 2; ++i) {
    float4 q = wq[lane * 2 + i], sv = sp[lane * 2 + i];
    acc += q.x * sv.x * sv.x + q.y * sv.y * sv.y + q.z * sv.z * sv.z + q.w * sv.w * sv.w;
  }
#pragma unroll
  for (int d = 32; d >= 1; d >>= 1) acc += __shfl_xor(acc, d, 64);
  if (lane == 0) dcoef[o] = rsqrtf(acc + 1e-8f);
}

// xT[b][h][w][fi] = bf16(x[b][fi][h][w] * s[b][fi])
__global__ void k_modx(const float* __restrict__ x, const float* __restrict__ s,
                       bf16_t* __restrict__ xT) {
  __shared__ float tile[32][65];
  int b = blockIdx.z;
  int fi0 = blockIdx.x * 32;
  int hw0 = blockIdx.y * 64;
  int t = threadIdx.x;
  int tx = t & 63, ty = t >> 6;
#pragma unroll
  for (int i = 0; i < 8; ++i) {
    int fi_l = i * 4 + ty;
    float sv = s[b * 512 + fi0 + fi_l];
    tile[fi_l][tx] = x[((size_t)(b * 512 + fi0 + fi_l)) * HW_ + hw0 + tx] * sv;
  }
  __syncthreads();
  int kx = t & 31, ky = t >> 5;
#pragma unroll
  for (int j = 0; j < 8; ++j) {
    int hw_l = j * 8 + ky;
    xT[((size_t)(b * HW_ + hw0 + hw_l)) * 512 + fi0 + kx] = (bf16_t)tile[kx][hw_l];
  }
}

// Main: 128-thread block (2 waves), tile 128 fo x 128 px (rows 2hq, 2hq+1).
// Wave wv owns row 2hq+wv (64 px), all 128 fo. LDS 16KB/buffer, dbuf.
// 144 its = 9 taps x 16 fi-chunks of 32; prefetch(it+1) after barrier.
__global__ __launch_bounds__(128, 2) void k_conv(const bf16_t* __restrict__ wt,
                                                 const bf16_t* __restrict__ xT,
                                                 const float* __restrict__ dcoef,
                                                 const bf16_t* __restrict__ zerobuf,
                                                 float* __restrict__ out) {
  __shared__ __align__(16) bf16_t xls[2][4 * 2 * 64 * 8];   // [p][c][row][px][8]  8KB
  __shared__ __align__(16) bf16_t wls[2][4 * 128 * 8];      // [p][c][fo][8]       8KB

  int b   = blockIdx.x;                 // 0..7  (linear%8=b -> XCD-pinned batch)
  int foB = blockIdx.y;                 // 0..3
  int hq  = blockIdx.z;                 // 0..31 -> rows 2hq, 2hq+1
  int t = threadIdx.x;                  // 0..127
  int wv = t >> 6, lane = t & 63, quad = lane >> 4, l16 = lane & 15;
  int h0 = hq * 2;

  const bf16_t* wtfoB = wt + (size_t)foB * 128 * 512;
  const bf16_t* xTb   = xT + (size_t)b * HW_ * 512;

  floatx4 acc[8][4];
#pragma unroll
  for (int i = 0; i < 8; ++i)
#pragma unroll
    for (int j = 0; j < 4; ++j) acc[i][j] = (floatx4){0.f, 0.f, 0.f, 0.f};

  auto stage = [&](int it, int p) {
    int tap = it >> 4;
    int fi0 = (it & 15) << 5;
    int kh = tap / 3, kw = tap - kh * 3;
    int rg = h0 + wv + kh - 1;          // wave-uniform source row
    int cg = lane + kw - 1;             // per-lane source col
    bool valid = ((unsigned)rg < 64u) && ((unsigned)cg < 64u);
    const bf16_t* xsrc0 = valid ? (xTb + ((size_t)(rg * 64 + cg)) * 512 + fi0)
                                : zerobuf;
    const bf16_t* wbase = wtfoB + (size_t)tap * 512 * 512 + fi0;
    // w: 512 granules (c,fo); instr itw=c, wave wv covers fo=wv*64+lane
#pragma unroll
    for (int itw = 0; itw < 4; ++itw)
      gload_lds16(wbase + (size_t)t * 512 + itw * 8,
                  &wls[p][(itw * 128 + wv * 64) * 8]);
    // x: instr it4=c; wave wv stages its own row, lane=px
#pragma unroll
    for (int it4 = 0; it4 < 4; ++it4) {
      const bf16_t* src = valid ? (xsrc0 + it4 * 8) : zerobuf;
      gload_lds16(src, &xls[p][((it4 * 2 + wv) * 64) * 8]);
    }
  };

  stage(0, 0);                          // prologue prefetch

  for (int it = 0; it < 144; ++it) {
    int p = it & 1;
    __syncthreads();                    // drains prefetch(it); protects LDS
    if (it + 1 < 144) stage(it + 1, p ^ 1);

    bf16x8 bfr[4];
#pragma unroll
    for (int j = 0; j < 4; ++j)
      bfr[j] = *(const bf16x8*)&xls[p][((quad * 2 + wv) * 64 + j * 16 + l16) * 8];
#pragma unroll
    for (int i = 0; i < 8; ++i) {
      bf16x8 afr = *(const bf16x8*)&wls[p][(quad * 128 + i * 16 + l16) * 8];
#pragma unroll
      for (int j = 0; j < 4; ++j)
        acc[i][j] = __builtin_amdgcn_mfma_f32_16x16x32_bf16(afr, bfr[j], acc[i][j], 0, 0, 0);
    }
  }

  // epilogue: C/D col=lane&15 (n=px), row=quad*4+reg (m=fo); scale by demod
  int h = h0 + wv;
#pragma unroll
  for (int i = 0; i < 8; ++i) {
#pragma unroll
    for (int rr = 0; rr < 4; ++rr) {
      int fo_g = foB * 128 + i * 16 + quad * 4 + rr;
      float dm = dcoef[b * 512 + fo_g];
      float* op = out + ((size_t)((b * 512 + fo_g) * 64 + h)) * 64;
#pragma unroll
      for (int j = 0; j < 4; ++j)
        op[j * 16 + l16] = acc[i][j][rr] * dm;
    }
  }
}

extern "C" void kernel_launch(void* const* d_in, const int* in_sizes, int n_in,
                              void* d_out, int out_size, void* d_ws, size_t ws_size,
                              hipStream_t stream) {
  const float* x     = (const float*)d_in[0];
  const float* style = (const float*)d_in[1];
  const float* w     = (const float*)d_in[2];
  const float* fc_w  = (const float*)d_in[3];
  const float* fc_b  = (const float*)d_in[4];
  float* out = (float*)d_out;
  char* ws = (char*)d_ws;

  float*  s       = (float*)(ws);                  // 16 KB
  float*  dcoef   = (float*)(ws + 16384);          // 16 KB
  float*  wsq     = (float*)(ws + 32768);          // 1 MB
  bf16_t* zerobuf = (bf16_t*)(ws + 1081344);       // 256 B of zeros
  bf16_t* wt      = (bf16_t*)(ws + 1081600);       // 4.5 MB  [tap][fo][fi]
  bf16_t* xT      = (bf16_t*)(ws + 5800192);       // 32 MB   [b][h][w][fi]

  hipMemsetAsync(zerobuf, 0, 256, stream);
  k_style<<<1024, 256, 0, stream>>>(style, fc_w, fc_b, s);
  k_wsq_wt<<<1024, 256, 0, stream>>>(w, wsq, wt);
  k_demod<<<1024, 256, 0, stream>>>(wsq, s, dcoef);
  k_modx<<<dim3(16, 64, 8), 256, 0, stream>>>(x, s, xT);
  // grid.x = b -> linear block id % 8 == b -> XCD-pinned batch slice
  k_conv<<<dim3(8, 4, 32), 128, 0, stream>>>(wt, xT, dcoef, zerobuf, out);
}

// Round 5
// 276.402 us; speedup vs baseline: 1.5799x; 1.5799x over previous
//
#include <hip/hip_runtime.h>

// modConv: y = demod(b,fo) * conv3x3(x * s(b,fi), w * w_scale)
// bf16 MFMA implicit GEMM (M=fo, N=pixels, K=fi, 9 taps accumulated).
// R5: R4's contiguous staging layouts (xT[b][h][g][w][8], wt[tap][g][fo][8];
//     every global_load_lds = one contiguous 1KB span) with prep kernels
//     UNFUSED back to the R3-validated k_style/k_wsq_wt/k_demod bodies.
//     k_conv geometry: 256-thr blocks, 128fo x 256px, dbuf, XCD=b swizzle.

typedef __bf16 bf16_t;
typedef __bf16 bf16x8 __attribute__((ext_vector_type(8)));
typedef float floatx4 __attribute__((ext_vector_type(4)));

#define HW_ 4096
#define FCSCALE 0.04419417382415922f   /* 512^-0.5 */
#define WSCALE  0.014731391274719742f  /* (512*9)^-0.5 */

__device__ __forceinline__ void gload_lds16(const bf16_t* g, bf16_t* l) {
  __builtin_amdgcn_global_load_lds(
      (const __attribute__((address_space(1))) void*)g,
      (__attribute__((address_space(3))) void*)l, 16, 0, 0);
}

// s[o] for o=b*512+fi: one wave per output, coalesced 2KB row read, shfl reduce
__global__ void k_style(const float* __restrict__ style, const float* __restrict__ fc_w,
                        const float* __restrict__ fc_b, float* __restrict__ s_out) {
  int o = blockIdx.x * 4 + (threadIdx.x >> 6);  // 0..4095
  int lane = threadIdx.x & 63;
  int b = o >> 9, fi = o & 511;
  const float4* st = (const float4*)(style + b * 512);
  const float4* fw = (const float4*)(fc_w + (size_t)fi * 512);
  float4 a0 = st[lane * 2],     w0 = fw[lane * 2];
  float4 a1 = st[lane * 2 + 1], w1 = fw[lane * 2 + 1];
  float acc = a0.x * w0.x + a0.y * w0.y + a0.z * w0.z + a0.w * w0.w
            + a1.x * w1.x + a1.y * w1.y + a1.z * w1.z + a1.w * w1.w;
#pragma unroll
  for (int d = 32; d >= 1; d >>= 1) acc += __shfl_xor(acc, d, 64);
  if (lane == 0) s_out[o] = acc * FCSCALE + fc_b[fi];
}

// wsq[fo][fi] = sum_tap (w*ws)^2 ; wt[tap][fi>>3][fo][fi&7] = bf16(w*ws)
__global__ void k_wsq_wt(const float* __restrict__ w, float* __restrict__ wsq,
                         bf16_t* __restrict__ wt) {
  int idx = blockIdx.x * 256 + threadIdx.x;     // fo*512+fi
  int fo = idx >> 9, fi = idx & 511;
  const float* wp = w + (size_t)idx * 9;
  float v[9], q = 0.f;
#pragma unroll
  for (int k = 0; k < 9; ++k) { v[k] = wp[k] * WSCALE; q += v[k] * v[k]; }
  wsq[idx] = q;
#pragma unroll
  for (int k = 0; k < 9; ++k)
    wt[((((size_t)k * 64) + (fi >> 3)) * 512 + fo) * 8 + (fi & 7)] = (bf16_t)v[k];
}

// d[o] = rsqrt(sum_fi wsq[fo][fi]*s[b][fi]^2 + eps): wave per output
__global__ void k_demod(const float* __restrict__ wsq, const float* __restrict__ s,
                        float* __restrict__ dcoef) {
  int o = blockIdx.x * 4 + (threadIdx.x >> 6);  // 0..4095 = b*512+fo
  int lane = threadIdx.x & 63;
  int b = o >> 9, fo = o & 511;
  const float4* wq = (const float4*)(wsq + (size_t)fo * 512);
  const float4* sp = (const float4*)(s + b * 512);
  float acc = 0.f;
#pragma unroll
  for (int i = 0; i < 2; ++i) {
    float4 q = wq[lane * 2 + i], sv = sp[lane * 2 + i];
    acc += q.x * sv.x * sv.x + q.y * sv.y * sv.y + q.z * sv.z * sv.z + q.w * sv.w * sv.w;
  }
#pragma unroll
  for (int d = 32; d >= 1; d >>= 1) acc += __shfl_xor(acc, d, 64);
  if (lane == 0) dcoef[o] = rsqrtf(acc + 1e-8f);
}

// xT[b][h][g][w][8] = bf16(x[b][g*8+j][h][w] * s)   (granule-major rows)
__global__ void k_modx(const float* __restrict__ x, const float* __restrict__ s,
                       bf16_t* __restrict__ xT) {
  __shared__ float tile[32][65];
  int b = blockIdx.z;
  int fi0 = blockIdx.x * 32;
  int h = blockIdx.y;                            // one image row (64 px)
  int t = threadIdx.x;
  int c4 = (t & 15) * 4, fr = t >> 4;            // float4 coalesced reads
#pragma unroll
  for (int i = 0; i < 2; ++i) {
    int fi_l = i * 16 + fr;
    float sv = s[b * 512 + fi0 + fi_l];
    float4 v = *(const float4*)(x + ((size_t)(b * 512 + fi0 + fi_l)) * HW_ + h * 64 + c4);
    tile[fi_l][c4] = v.x * sv; tile[fi_l][c4 + 1] = v.y * sv;
    tile[fi_l][c4 + 2] = v.z * sv; tile[fi_l][c4 + 3] = v.w * sv;
  }
  __syncthreads();
  int g_l = t >> 6, wcol = t & 63;               // write granule (g_l) x col
  bf16x8 vv;
#pragma unroll
  for (int j = 0; j < 8; ++j) vv[j] = (bf16_t)tile[g_l * 8 + j][wcol];
  *(bf16x8*)&xT[((((size_t)(b * 64 + h)) * 64 + (fi0 >> 3) + g_l) * 64 + wcol) * 8] = vv;
}

// Main: block = 128 fo x 256 px (4 rows h0..h0+3), 4 waves each 128 fo x 64 px.
// 144 its = 9 taps x 16 fi-chunks of 32; dbuf LDS, prefetch(it+1) after barrier.
// All staging loads are contiguous 1KB spans (edge lanes -> zerobuf).
__global__ __launch_bounds__(256, 2) void k_conv(const bf16_t* __restrict__ wt,
                                                 const bf16_t* __restrict__ xT,
                                                 const float* __restrict__ dcoef,
                                                 const bf16_t* __restrict__ zerobuf,
                                                 float* __restrict__ out) {
  __shared__ __align__(16) bf16_t xls[2][4 * 256 * 8];   // [p][c][px 256][8]  16KB
  __shared__ __align__(16) bf16_t wls[2][4 * 128 * 8];   // [p][c][fo 128][8]   8KB

  int b   = blockIdx.x;                 // 0..7  (linear%8=b -> XCD-pinned batch)
  int foB = blockIdx.y;                 // 0..3
  int hq  = blockIdx.z;                 // 0..15 -> rows h0..h0+3
  int t = threadIdx.x;
  int wv = t >> 6, lane = t & 63, quad = lane >> 4, l16 = lane & 15;
  int h0 = hq * 4;
  int fo_l = t & 127, chunk_hi = t >> 7;

  const bf16_t* xTb = xT + (size_t)b * 64 * 64 * 64 * 8;   // [h][g][w][8]

  floatx4 acc[8][4];
#pragma unroll
  for (int i = 0; i < 8; ++i)
#pragma unroll
    for (int j = 0; j < 4; ++j) acc[i][j] = (floatx4){0.f, 0.f, 0.f, 0.f};

  auto stage = [&](int it, int p) {
    int tap = it >> 4;
    int g0 = (it & 15) * 4;             // fi-granule base (granule = 8 fi)
    int kh = tap / 3, kw = tap - kh * 3;
    int rg = h0 + wv + kh - 1;          // wave-uniform source row
    int cg = lane + kw - 1;             // per-lane source col
    bool valid = ((unsigned)rg < 64u) && ((unsigned)cg < 64u);
    // w: [tap][g][fo][8]; instr itw -> granule cw; lanes = consecutive fo -> 1KB
#pragma unroll
    for (int itw = 0; itw < 2; ++itw) {
      int cw = itw * 2 + chunk_hi;
      gload_lds16(wt + ((((size_t)tap * 64) + g0 + cw) * 512 + foB * 128 + fo_l) * 8,
                  &wls[p][(itw * 256 + wv * 64) * 8]);
    }
    // x: [h][g][w][8]; instr it4 -> granule; lanes = consecutive cols -> 1KB
#pragma unroll
    for (int it4 = 0; it4 < 4; ++it4) {
      const bf16_t* src = valid
          ? xTb + (((size_t)rg * 64 + g0 + it4) * 64 + cg) * 8
          : zerobuf;
      gload_lds16(src, &xls[p][(it4 * 256 + wv * 64) * 8]);
    }
  };

  stage(0, 0);                          // prologue prefetch

  for (int it = 0; it < 144; ++it) {
    int p = it & 1;
    __syncthreads();                    // drains prefetch(it); protects LDS
    if (it + 1 < 144) stage(it + 1, p ^ 1);

    bf16x8 bfr[4];
#pragma unroll
    for (int j = 0; j < 4; ++j)
      bfr[j] = *(const bf16x8*)&xls[p][(quad * 256 + wv * 64 + j * 16 + l16) * 8];
#pragma unroll
    for (int i = 0; i < 8; ++i) {
      bf16x8 afr = *(const bf16x8*)&wls[p][(quad * 128 + i * 16 + l16) * 8];
#pragma unroll
      for (int j = 0; j < 4; ++j)
        acc[i][j] = __builtin_amdgcn_mfma_f32_16x16x32_bf16(afr, bfr[j], acc[i][j], 0, 0, 0);
    }
  }

  // epilogue: C/D col=lane&15 (n=px), row=quad*4+reg (m=fo); scale by demod
  int h = h0 + wv;
#pragma unroll
  for (int i = 0; i < 8; ++i) {
#pragma unroll
    for (int rr = 0; rr < 4; ++rr) {
      int fo_g = foB * 128 + i * 16 + quad * 4 + rr;
      float dm = dcoef[b * 512 + fo_g];
      float* op = out + ((size_t)((b * 512 + fo_g) * 64 + h)) * 64;
#pragma unroll
      for (int j = 0; j < 4; ++j)
        op[j * 16 + l16] = acc[i][j][rr] * dm;
    }
  }
}

extern "C" void kernel_launch(void* const* d_in, const int* in_sizes, int n_in,
                              void* d_out, int out_size, void* d_ws, size_t ws_size,
                              hipStream_t stream) {
  const float* x     = (const float*)d_in[0];
  const float* style = (const float*)d_in[1];
  const float* w     = (const float*)d_in[2];
  const float* fc_w  = (const float*)d_in[3];
  const float* fc_b  = (const float*)d_in[4];
  float* out = (float*)d_out;
  char* ws = (char*)d_ws;

  float*  s       = (float*)(ws);                  // 16 KB
  float*  dcoef   = (float*)(ws + 16384);          // 16 KB
  float*  wsq     = (float*)(ws + 32768);          // 1 MB
  bf16_t* zerobuf = (bf16_t*)(ws + 1081344);       // 256 B of zeros
  bf16_t* wt      = (bf16_t*)(ws + 1081600);       // 4.5 MB  [tap][g][fo][8]
  bf16_t* xT      = (bf16_t*)(ws + 5800192);       // 32 MB   [b][h][g][w][8]

  hipMemsetAsync(zerobuf, 0, 256, stream);
  k_style<<<1024, 256, 0, stream>>>(style, fc_w, fc_b, s);
  k_wsq_wt<<<1024, 256, 0, stream>>>(w, wsq, wt);
  k_demod<<<1024, 256, 0, stream>>>(wsq, s, dcoef);
  k_modx<<<dim3(16, 64, 8), 256, 0, stream>>>(x, s, xT);
  // grid.x = b -> linear block id % 8 == b -> XCD-pinned batch slice
  k_conv<<<dim3(8, 4, 16), 256, 0, stream>>>(wt, xT, dcoef, zerobuf, out);
}